// Round 2
// baseline (212.127 us; speedup 1.0000x reference)
//
#include <hip/hip_runtime.h>

// Problem constants
#define BB 2
#define NRES 192
#define NATOMS 4
#define NN 768            // N = NRES*NATOMS
#define NODE_DIM 128
#define EDGE_DIM 64
#define NUM_RBF 32

// Output layout (float32 elements, concatenated flat in return order)
#define NODE_OFF   ((size_t)0)
#define EDGE_OFF   ((size_t)196608)                 // 2*768*128
#define COORDS_OFF ((size_t)(196608 + 75497472))    // + 2*768*768*64
#define MASK_OFF   ((size_t)(COORDS_OFF + 4608))    // + 2*768*3

__device__ __forceinline__ float silu(float x) { return x / (1.0f + expf(-x)); }

// ---------------------------------------------------------------------------
// Node kernel: one block (128 threads) per residue (B*NRES = 384 blocks).
// Computes mutation MLP once per residue, then node MLP for its 4 atoms.
// Also copies coords_flat and atom_mask_flat outputs.
// ---------------------------------------------------------------------------
__global__ __launch_bounds__(128) void node_kernel(
    const float* __restrict__ coords,
    const float* __restrict__ mut_mask,
    const float* __restrict__ atom_mask,
    const float* __restrict__ aa_emb,
    const float* __restrict__ atom_emb,
    const float* __restrict__ pos_emb,
    const float* __restrict__ aa_props,
    const float* __restrict__ mW1, const float* __restrict__ mb1,
    const float* __restrict__ mW2, const float* __restrict__ mb2,
    const float* __restrict__ nW1, const float* __restrict__ nb1,
    const float* __restrict__ nW2, const float* __restrict__ nb2,
    const int* __restrict__ wt_idx, const int* __restrict__ mut_idx,
    const int* __restrict__ res_idx,
    float* __restrict__ out)
{
    __shared__ float s_in[128];   // mut_in (124 used)
    __shared__ float s_h[128];    // hidden (64 or 128 used)
    __shared__ float s_res[96];   // res_feat (94 used)
    __shared__ float s_nin[128];  // node_in (126 used)

    const int blk = blockIdx.x;   // b*192 + r
    const int t = threadIdx.x;

    const int wt = wt_idx[blk];
    const int mu = mut_idx[blk];
    const float mm = mut_mask[blk];

    // stage mut_in = [wt_e(32), mut_e(32), wt_p(30), mut_p(30)]
    if (t < 32) { s_in[t] = aa_emb[wt * 32 + t]; s_in[32 + t] = aa_emb[mu * 32 + t]; }
    if (t < 30) { s_in[64 + t] = aa_props[wt * 30 + t]; s_in[94 + t] = aa_props[mu * 30 + t]; }
    __syncthreads();

    // mut hidden (64)
    if (t < 64) {
        float acc = mb1[t];
        for (int k = 0; k < 124; ++k) acc += s_in[k] * mW1[k * 64 + t];
        s_h[t] = silu(acc);
    }
    __syncthreads();

    // mut_feat (32) * mask; res_feat = [wt_e(0..31), wt_p(32..61), mut_feat(62..93)]
    if (t < 32) {
        float acc = mb2[t];
        for (int k = 0; k < 64; ++k) acc += s_h[k] * mW2[k * 32 + t];
        s_res[62 + t] = acc * mm;
        s_res[t] = s_in[t];
    }
    if (t < 30) s_res[32 + t] = s_in[64 + t];
    __syncthreads();

    for (int a = 0; a < 4; ++a) {
        const int gn = blk * 4 + a;   // b*768 + n
        // node_in = [res_feat(94), atom_emb[a](16), pos_emb[res_idx](16)]
        if (t < 94) s_nin[t] = s_res[t];
        else if (t < 110) s_nin[t] = atom_emb[a * 16 + (t - 94)];
        else if (t < 126) s_nin[t] = pos_emb[res_idx[gn] * 16 + (t - 110)];
        __syncthreads();

        float acc = nb1[t];
        for (int k = 0; k < 126; ++k) acc += s_nin[k] * nW1[k * 128 + t];
        float h = silu(acc);
        __syncthreads();
        s_h[t] = h;
        __syncthreads();

        float o = nb2[t];
        for (int k = 0; k < 128; ++k) o += s_h[k] * nW2[k * 128 + t];
        const float am = atom_mask[gn];
        out[NODE_OFF + (size_t)gn * 128 + t] = o * am;
        __syncthreads();  // protect s_nin/s_h before next atom
    }

    // coords_flat passthrough (12 floats per residue) and atom_mask_flat (4)
    if (t < 12) out[COORDS_OFF + (size_t)blk * 12 + t] = coords[(size_t)blk * 12 + t];
    if (t < 4)  out[MASK_OFF + (size_t)blk * 4 + t]  = atom_mask[(size_t)blk * 4 + t];
}

// ---------------------------------------------------------------------------
// Edge kernel: one block (256 threads = 4 waves) per output row (b, i).
// Wave handles groups of 8 consecutive j. All-nonadjacent group -> 2 KiB
// zero-fill with uint4 stores. Adjacent pair -> wave-cooperative MLP
// (64 lanes = 64 channels) with weights in LDS, cross-lane via shfl.
// ---------------------------------------------------------------------------
__global__ __launch_bounds__(256) void edge_kernel(
    const float* __restrict__ coords,
    const float* __restrict__ atom_mask,
    const float* __restrict__ eW1, const float* __restrict__ eb1,
    const float* __restrict__ eW2, const float* __restrict__ eb2,
    float* __restrict__ out)
{
    __shared__ float xs[NN], ys[NN], zs[NN], ms[NN];
    __shared__ float W1[NUM_RBF * 64];
    __shared__ float W2[64 * 64];
    __shared__ float b1[64], b2[64];

    const int blk = blockIdx.x;
    const int b = blk / NN;
    const int i = blk % NN;
    const int t = threadIdx.x;

    const float* cb = coords + (size_t)b * NN * 3;
    for (int n = t; n < NN; n += 256) {
        xs[n] = cb[n * 3 + 0];
        ys[n] = cb[n * 3 + 1];
        zs[n] = cb[n * 3 + 2];
        ms[n] = atom_mask[(size_t)b * NN + n];
    }
    for (int k = t; k < NUM_RBF * 64; k += 256) W1[k] = eW1[k];
    for (int k = t; k < 64 * 64; k += 256)      W2[k] = eW2[k];
    if (t < 64) { b1[t] = eb1[t]; b2[t] = eb2[t]; }
    __syncthreads();

    const int lane = t & 63;
    const int wv = t >> 6;
    const float xi = xs[i], yi = ys[i], zi = zs[i], mi = ms[i];
    float* rowp = out + EDGE_OFF + ((size_t)b * NN + i) * (size_t)NN * EDGE_DIM;

    for (int g = wv; g < NN / 8; g += 4) {
        const int j0 = g * 8;
        const int jj = j0 + (lane & 7);
        const float dx = xi - xs[jj];
        const float dy = yi - ys[jj];
        const float dz = zi - zs[jj];
        const float dist = sqrtf(dx * dx + dy * dy + dz * dz + 1e-8f);
        const float mprod = mi * ms[jj];
        const bool adj = (dist <= 7.5f) && (jj != i) && (mprod != 0.0f);
        const unsigned long long bal = __ballot(adj && (lane < 8));
        float* gp = rowp + (size_t)j0 * EDGE_DIM;

        if (bal == 0ULL) {
            // 8 pairs * 64ch * 4B = 2048B of zeros; 64 lanes * 2 * 16B
            ((uint4*)gp)[lane] = make_uint4(0u, 0u, 0u, 0u);
            ((uint4*)gp)[lane + 64] = make_uint4(0u, 0u, 0u, 0u);
        } else {
            for (int p = 0; p < 8; ++p) {
                float* pp = gp + p * EDGE_DIM;
                if ((bal >> p) & 1ULL) {
                    const float d = __shfl(dist, p);
                    const float mf = __shfl(mprod, p);
                    // my rbf value for k = lane&31 (lanes 32..63 duplicate)
                    const float ck = (float)(lane & 31) * (20.0f / 31.0f);
                    const float dd = d - ck;
                    const float my_r = expf(-(dd * dd) / 0.78125f);  // 2*gamma^2
                    // hidden[lane] = silu(b1 + sum_k rbf_k * W1[k][lane])
                    float acc = b1[lane];
                    #pragma unroll
                    for (int k = 0; k < 32; ++k) {
                        const float rk = __shfl(my_r, k);
                        acc += rk * W1[k * 64 + lane];
                    }
                    const float h = silu(acc);
                    // out[lane] = b2 + sum_h hidden_h * W2[h][lane]
                    float o = b2[lane];
                    for (int hh = 0; hh < 64; ++hh) {
                        const float hv = __shfl(h, hh);
                        o += hv * W2[hh * 64 + lane];
                    }
                    pp[lane] = o * mf;
                } else {
                    ((unsigned int*)pp)[lane] = 0u;
                }
            }
        }
    }
}

extern "C" void kernel_launch(void* const* d_in, const int* in_sizes, int n_in,
                              void* d_out, int out_size, void* d_ws, size_t ws_size,
                              hipStream_t stream) {
    const float* coords    = (const float*)d_in[0];
    const float* mut_mask  = (const float*)d_in[1];
    const float* atom_mask = (const float*)d_in[2];
    const float* aa_emb    = (const float*)d_in[3];
    const float* atom_emb  = (const float*)d_in[4];
    const float* pos_emb   = (const float*)d_in[5];
    const float* aa_props  = (const float*)d_in[6];
    const float* mut_W1    = (const float*)d_in[7];
    const float* mut_b1    = (const float*)d_in[8];
    const float* mut_W2    = (const float*)d_in[9];
    const float* mut_b2    = (const float*)d_in[10];
    const float* node_W1   = (const float*)d_in[11];
    const float* node_b1   = (const float*)d_in[12];
    const float* node_W2   = (const float*)d_in[13];
    const float* node_b2   = (const float*)d_in[14];
    const float* edge_W1   = (const float*)d_in[15];
    const float* edge_b1   = (const float*)d_in[16];
    const float* edge_W2   = (const float*)d_in[17];
    const float* edge_b2   = (const float*)d_in[18];
    const int* wt_indices  = (const int*)d_in[19];
    const int* mut_indices = (const int*)d_in[20];
    const int* res_indices = (const int*)d_in[21];

    float* out = (float*)d_out;

    node_kernel<<<BB * NRES, 128, 0, stream>>>(
        coords, mut_mask, atom_mask, aa_emb, atom_emb, pos_emb, aa_props,
        mut_W1, mut_b1, mut_W2, mut_b2, node_W1, node_b1, node_W2, node_b2,
        wt_indices, mut_indices, res_indices, out);

    edge_kernel<<<BB * NN, 256, 0, stream>>>(
        coords, atom_mask, edge_W1, edge_b1, edge_W2, edge_b2, out);
}